// Round 7
// baseline (195.144 us; speedup 1.0000x reference)
//
#include <hip/hip_runtime.h>
#include <stdint.h>

#define N_       8
#define IC_      16
#define C1_      2048
#define H_       56
#define W_       56

typedef float    vf4 __attribute__((ext_vector_type(4)));
typedef uint32_t vu2 __attribute__((ext_vector_type(2)));

__device__ __forceinline__ uint32_t cvt_pk_bf16(float lo, float hi) {
    uint32_t r;
    asm("v_cvt_pk_bf16_f32 %0, %1, %2" : "=v"(r) : "v"(lo), "v"(hi));
    return r;   // [15:0]=bf16(lo) [31:16]=bf16(hi), RNE
}

#define LO_(u) __uint_as_float((u) << 16)
#define HI_(u) __uint_as_float((u) & 0xffff0000u)

// ================= Kernel A: grouped 3x3 conv -> out1 bf16, layout (n,h,c,w) =================
// grid = (n*56+h)*8 + s ; thread: c = s*256 + (tid&255), half = tid>>8 (wave-uniform).
// All window loads are wave-uniform -> scalar path; stores dense 28KB window per block.
__global__ __launch_bounds__(512, 2)
void conv_a(const float* __restrict__ x, const float* __restrict__ W1,
            const float* __restrict__ b1, uint32_t* __restrict__ out1)
{
    const int tid  = threadIdx.x;
    const int b    = blockIdx.x;
    const int s    = b & 7;
    const int t2   = b >> 3;                 // n*56 + h
    const int h    = t2 % H_;
    const int n    = t2 / H_;
    const int c    = s * 256 + (tid & 255);
    const int half = __builtin_amdgcn_readfirstlane(tid >> 8);   // 0/1, wave-uniform
    const int ci   = __builtin_amdgcn_readfirstlane(c >> 7);     // wave-uniform input ch
    const int w0   = half * 28;

    const float* xb = x + (size_t)((n * IC_ + ci) * H_) * W_;
    float win[3][30];                        // cols w0-1 .. w0+28 (uniform -> SGPRs)
    #pragma unroll
    for (int rr = 0; rr < 3; ++rr) {
        const int r = h - 1 + rr;
        if ((unsigned)r < (unsigned)H_) {    // uniform branch
            const float* rp = xb + r * W_ + w0;
            win[rr][0] = (half == 0) ? 0.0f : rp[-1];
            #pragma unroll
            for (int v = 0; v < 7; ++v) {    // 16B-aligned float4 loads
                const vf4 t = *(const vf4*)(rp + 4 * v);
                win[rr][1+4*v] = t.x; win[rr][2+4*v] = t.y;
                win[rr][3+4*v] = t.z; win[rr][4+4*v] = t.w;
            }
            win[rr][29] = (half == 1) ? 0.0f : rp[28];
        } else {
            #pragma unroll
            for (int k = 0; k < 30; ++k) win[rr][k] = 0.0f;
        }
    }

    float w[9];
    const float* wp = W1 + c * 9;
    #pragma unroll
    for (int k = 0; k < 9; ++k) w[k] = wp[k];
    const float bias = b1[c];

    float acc[28];
    #pragma unroll
    for (int p = 0; p < 28; ++p) acc[p] = bias;
    #pragma unroll
    for (int dr = 0; dr < 3; ++dr)
        #pragma unroll
        for (int dc = 0; dc < 3; ++dc) {
            const float wk = w[dr * 3 + dc];
            #pragma unroll
            for (int p = 0; p < 28; ++p)
                acc[p] = fmaf(win[dr][p + dc], wk, acc[p]);
        }

    // out1 row (n,h,c) = 28 dwords of bf16 pairs; this thread writes dwords half*14..+13
    uint32_t* rowp = out1 + ((size_t)t2 * C1_ + c) * 28 + half * 14;
    #pragma unroll
    for (int k = 0; k < 7; ++k) {
        vu2 pr;
        pr.x = cvt_pk_bf16(acc[4*k + 0], acc[4*k + 1]);
        pr.y = cvt_pk_bf16(acc[4*k + 2], acc[4*k + 3]);
        *(vu2*)(rowp + 2 * k) = pr;          // b64 store, dense block window
    }
}

// ================= Kernel B: gather + max-over-4 -> out (n,j,h,w) =================
// grid = (n*28+h2)*8 + sj ; block owns h-pair (2*h2, 2*h2+1) x 256 output channels.
// Lanes q-fastest: 28 consecutive lanes write one j's 448B = 7 full aligned lines.
__global__ __launch_bounds__(512, 4)
void gmax_b(const uint32_t* __restrict__ out1, const int* __restrict__ idx,
            float* __restrict__ out)
{
    const int tid = threadIdx.x;
    const int b   = blockIdx.x;
    const int sj  = b & 7;
    const int t2  = b >> 3;                  // n*28 + h2
    const int h2  = t2 % 28;
    const int n   = t2 / 28;

    for (int it = 0; it < 14; ++it) {
        const int f   = it * 512 + tid;      // [0, 7168) over (j_local, q)
        const int jl  = f / 28;              // compiler magic-div
        const int q   = f - jl * 28;
        const int j   = sj * 256 + jl;
        const int ho  = (q >= 14) ? 1 : 0;
        const int q14 = q - ho * 14;
        const int h   = h2 * 2 + ho;

        const int4 iv = *(const int4*)(idx + 4 * j);     // broadcast across 28 lanes

        const uint32_t* pb = out1 + (size_t)(n * H_ + h) * C1_ * 28 + q14 * 2;
        const vu2 a = *(const vu2*)(pb + (size_t)(iv.x & (C1_-1)) * 28);
        const vu2 bq= *(const vu2*)(pb + (size_t)(iv.y & (C1_-1)) * 28);
        const vu2 cq= *(const vu2*)(pb + (size_t)(iv.z & (C1_-1)) * 28);
        const vu2 dq= *(const vu2*)(pb + (size_t)(iv.w & (C1_-1)) * 28);

        vf4 o;
        o.x = fmaxf(fmaxf(LO_(a.x), LO_(bq.x)), fmaxf(LO_(cq.x), LO_(dq.x)));
        o.y = fmaxf(fmaxf(HI_(a.x), HI_(bq.x)), fmaxf(HI_(cq.x), HI_(dq.x)));
        o.z = fmaxf(fmaxf(LO_(a.y), LO_(bq.y)), fmaxf(LO_(cq.y), LO_(dq.y)));
        o.w = fmaxf(fmaxf(HI_(a.y), HI_(bq.y)), fmaxf(HI_(cq.y), HI_(dq.y)));

        float* op = out + ((size_t)(n * C1_ + j) * H_ + h) * W_ + q14 * 4;
        *(vf4*)op = o;                       // 16B-aligned; 28-lane runs = full lines
    }
}

// ================= Fallback: fused single-kernel (round-6, 89us) if ws too small =================
template <int CLS>
__device__ __forceinline__ void fbody(uint32_t* __restrict__ s1, const int tid,
                                      const int n, const int h, const int w0,
                                      const float* __restrict__ x,
                                      const float* __restrict__ W1,
                                      const float* __restrict__ b1,
                                      const int* __restrict__ idx,
                                      float* __restrict__ out)
{
    constexpr int TW = (CLS == 2) ? 8 : 12;
    constexpr int ND = TW / 2;

    float w[4][9], bias[4];
    #pragma unroll
    for (int p = 0; p < 4; ++p) {
        const float* wp = W1 + (p * 512 + tid) * 9;
        #pragma unroll
        for (int k = 0; k < 9; ++k) w[p][k] = wp[k];
        bias[p] = b1[p * 512 + tid];
    }
    #pragma unroll
    for (int p = 0; p < 4; ++p) {
        const int c  = p * 512 + tid;
        const int ci = __builtin_amdgcn_readfirstlane(c >> 7);
        const float* xb = x + (size_t)((n * IC_ + ci) * H_) * W_;
        float win[3][TW + 2];
        #pragma unroll
        for (int rr = 0; rr < 3; ++rr) {
            const int r = h - 1 + rr;
            if ((unsigned)r < (unsigned)H_) {
                const float* rp = xb + r * W_;
                win[rr][0] = (CLS == 0) ? 0.0f : rp[w0 - 1];
                #pragma unroll
                for (int v = 0; v < TW / 4; ++v) {
                    const vf4 t = *(const vf4*)(rp + w0 + 4 * v);
                    win[rr][1+4*v] = t.x; win[rr][2+4*v] = t.y;
                    win[rr][3+4*v] = t.z; win[rr][4+4*v] = t.w;
                }
                win[rr][TW + 1] = (CLS == 2) ? 0.0f : rp[w0 + TW];
            } else {
                #pragma unroll
                for (int k = 0; k < TW + 2; ++k) win[rr][k] = 0.0f;
            }
        }
        float acc[TW];
        #pragma unroll
        for (int q = 0; q < TW; ++q) acc[q] = bias[p];
        #pragma unroll
        for (int dr = 0; dr < 3; ++dr)
            #pragma unroll
            for (int dc = 0; dc < 3; ++dc) {
                const float wk = w[p][dr * 3 + dc];
                #pragma unroll
                for (int q = 0; q < TW; ++q)
                    acc[q] = fmaf(win[dr][q + dc], wk, acc[q]);
            }
        uint32_t* row = &s1[c * 6];
        #pragma unroll
        for (int m = 0; m < ND / 2; ++m) {
            vu2 pr;
            pr.x = cvt_pk_bf16(acc[4*m + 0], acc[4*m + 1]);
            pr.y = cvt_pk_bf16(acc[4*m + 2], acc[4*m + 3]);
            *(vu2*)(row + 2 * m) = pr;
        }
    }
    __syncthreads();
    #pragma unroll
    for (int p = 0; p < 4; ++p) {
        const int j = p * 512 + tid;
        const int4 iv = *(const int4*)(idx + 4 * j);
        const uint32_t* r0 = &s1[(iv.x & (C1_-1)) * 6];
        const uint32_t* r1 = &s1[(iv.y & (C1_-1)) * 6];
        const uint32_t* r2 = &s1[(iv.z & (C1_-1)) * 6];
        const uint32_t* r3 = &s1[(iv.w & (C1_-1)) * 6];
        float o[TW];
        #pragma unroll
        for (int m = 0; m < ND / 2; ++m) {
            const vu2 a = *(const vu2*)(r0 + 2*m);
            const vu2 b = *(const vu2*)(r1 + 2*m);
            const vu2 c = *(const vu2*)(r2 + 2*m);
            const vu2 d = *(const vu2*)(r3 + 2*m);
            o[4*m+0] = fmaxf(fmaxf(LO_(a.x), LO_(b.x)), fmaxf(LO_(c.x), LO_(d.x)));
            o[4*m+1] = fmaxf(fmaxf(HI_(a.x), HI_(b.x)), fmaxf(HI_(c.x), HI_(d.x)));
            o[4*m+2] = fmaxf(fmaxf(LO_(a.y), LO_(b.y)), fmaxf(LO_(c.y), LO_(d.y)));
            o[4*m+3] = fmaxf(fmaxf(HI_(a.y), HI_(b.y)), fmaxf(HI_(c.y), HI_(d.y)));
        }
        float* op = out + (size_t)(n * C1_ + j) * (H_ * W_) + h * W_ + w0;
        #pragma unroll
        for (int v = 0; v < TW / 4; ++v) {
            vf4 t; t.x = o[4*v]; t.y = o[4*v+1]; t.z = o[4*v+2]; t.w = o[4*v+3];
            *(vf4*)(op + 4 * v) = t;
        }
    }
}

__global__ __launch_bounds__(512, 6)
void rptn_fused(const float* __restrict__ x, const float* __restrict__ W1,
                const float* __restrict__ b1, const int* __restrict__ idx,
                float* __restrict__ out)
{
    __shared__ uint32_t s1[C1_ * 6];
    const int tid  = threadIdx.x;
    const int b    = blockIdx.x;
    const int wsel = b % 5;
    const int bh   = b / 5;
    const int n    = bh / H_;
    const int h    = bh % H_;
    if (wsel == 0)      fbody<0>(s1, tid, n, h, 0,        x, W1, b1, idx, out);
    else if (wsel == 4) fbody<2>(s1, tid, n, h, 48,       x, W1, b1, idx, out);
    else                fbody<1>(s1, tid, n, h, wsel*12,  x, W1, b1, idx, out);
}

extern "C" void kernel_launch(void* const* d_in, const int* in_sizes, int n_in,
                              void* d_out, int out_size, void* d_ws, size_t ws_size,
                              hipStream_t stream)
{
    const float* x   = (const float*)d_in[0];
    const float* W1  = (const float*)d_in[1];
    const float* b1  = (const float*)d_in[2];
    const int* idxp  = (const int*)d_in[3];
    float* out       = (float*)d_out;

    const size_t need = (size_t)N_ * H_ * C1_ * W_ * 2;   // 102,760,448 B for out1 bf16
    if (ws_size >= need) {
        uint32_t* out1 = (uint32_t*)d_ws;
        hipLaunchKernelGGL(conv_a, dim3(N_ * H_ * 8), dim3(512), 0, stream,
                           x, W1, b1, out1);
        hipLaunchKernelGGL(gmax_b, dim3(N_ * 28 * 8), dim3(512), 0, stream,
                           out1, idxp, out);
    } else {
        hipLaunchKernelGGL(rptn_fused, dim3(N_ * H_ * 5), dim3(512), 0, stream,
                           x, W1, b1, idxp, out);
    }
}

// Round 8
// 80.698 us; speedup vs baseline: 2.4182x; 2.4182x over previous
//
#include <hip/hip_runtime.h>
#include <stdint.h>

#define N_       8
#define IC_      16
#define C1_      2048
#define H_       56
#define W_       56
#define THREADS_ 512
#define ROWU_    8          // 8 dwords/row -> 64 KB total, 2 blocks/CU

typedef float    vf4 __attribute__((ext_vector_type(4)));
typedef uint32_t vu2 __attribute__((ext_vector_type(2)));

__device__ __forceinline__ uint32_t cvt_pk_bf16(float lo, float hi) {
    uint32_t r;
    asm("v_cvt_pk_bf16_f32 %0, %1, %2" : "=v"(r) : "v"(lo), "v"(hi));
    return r;   // [15:0]=bf16(lo) [31:16]=bf16(hi), RNE
}

#define LO_(u) __uint_as_float((u) << 16)
#define HI_(u) __uint_as_float((u) & 0xffff0000u)

// XOR pair-swizzle: rows r, r+4, r+8, r+12 (same 8-dword bank window) get
// distinct pair rotations -> phase-1 writes 16-way -> 4-way, reads <=4-way.
__device__ __forceinline__ int swz_pair(int row, int pair) {
    return (pair ^ (((row >> 2) & 3) << 1));
}

// CLS: 0 = w0=0 (16px, left col padded), 1 = w0=16/32 (interior),
//      2 = w0=48 (8px, right col padded)
template <int CLS>
__device__ __forceinline__ void body(uint32_t* __restrict__ s1, const int tid,
                                     const int n, const int h, const int w0,
                                     const float* __restrict__ x,
                                     const float* __restrict__ W1,
                                     const float* __restrict__ b1,
                                     const int* __restrict__ idx,
                                     float* __restrict__ out)
{
    constexpr int TW = (CLS == 2) ? 8 : 16;

    // ---- hoist weights + bias for all 4 passes (ILP: 40 loads in flight) ----
    float w[4][9], bias[4];
    #pragma unroll
    for (int p = 0; p < 4; ++p) {
        const float* wp = W1 + (p * THREADS_ + tid) * 9;
        #pragma unroll
        for (int k = 0; k < 9; ++k) w[p][k] = wp[k];
        bias[p] = b1[p * THREADS_ + tid];
    }

    // ---------------- Phase 1: grouped 3x3 conv -> LDS (bf16 pairs) ----------------
    #pragma unroll
    for (int p = 0; p < 4; ++p) {
        const int c  = p * THREADS_ + tid;
        const int ci = __builtin_amdgcn_readfirstlane(c >> 7);  // wave-uniform
        const float* xb = x + (size_t)((n * IC_ + ci) * H_) * W_;

        float win[3][TW + 2];
        #pragma unroll
        for (int rr = 0; rr < 3; ++rr) {
            const int r = h - 1 + rr;
            if ((unsigned)r < (unsigned)H_) {                   // uniform branch
                const float* rp = xb + r * W_;
                win[rr][0] = (CLS == 0) ? 0.0f : rp[w0 - 1];
                #pragma unroll
                for (int v = 0; v < TW / 4; ++v) {              // 16B-aligned f4 loads
                    const vf4 t = *(const vf4*)(rp + w0 + 4 * v);
                    win[rr][1 + 4*v] = t.x; win[rr][2 + 4*v] = t.y;
                    win[rr][3 + 4*v] = t.z; win[rr][4 + 4*v] = t.w;
                }
                win[rr][TW + 1] = (CLS == 2) ? 0.0f : rp[w0 + TW];
            } else {
                #pragma unroll
                for (int k = 0; k < TW + 2; ++k) win[rr][k] = 0.0f;
            }
        }

        float acc[TW];
        #pragma unroll
        for (int q = 0; q < TW; ++q) acc[q] = bias[p];
        #pragma unroll
        for (int dr = 0; dr < 3; ++dr)
            #pragma unroll
            for (int dc = 0; dc < 3; ++dc) {
                const float wk = w[p][dr * 3 + dc];
                #pragma unroll
                for (int q = 0; q < TW; ++q)
                    acc[q] = fmaf(win[dr][q + dc], wk, acc[q]);
            }

        uint32_t* row = &s1[c * ROWU_];
        #pragma unroll
        for (int m = 0; m < TW / 4; ++m) {
            vu2 pr;
            pr.x = cvt_pk_bf16(acc[4*m + 0], acc[4*m + 1]);
            pr.y = cvt_pk_bf16(acc[4*m + 2], acc[4*m + 3]);
            *(vu2*)(row + swz_pair(c, 2 * m)) = pr;            // ds_write_b64
        }
    }

    __syncthreads();

    // ---- Phase 2: PIXEL-MAJOR gather + max-over-4 + full-line float4 stores ----
    // 4 consecutive lanes (q=0..3) cover one j's 64B line -> 1 transaction/line.
    if (CLS != 2) {
        const int q  = tid & 3;                 // constant per thread
        const int j0 = tid >> 2;                // j walks j0 + 128*it
        const int* ivp = idx + 4 * j0;
        float* opb = out + (size_t)(n * C1_ + j0) * (H_ * W_) + h * W_ + w0 + 4 * q;
        #pragma unroll 4
        for (int it = 0; it < 16; ++it) {
            const int4 iv = *(const int4*)(ivp + it * 512);
            const int r0 = iv.x & (C1_-1), r1 = iv.y & (C1_-1);
            const int r2 = iv.z & (C1_-1), r3 = iv.w & (C1_-1);
            const vu2 a  = *(const vu2*)(&s1[r0 * ROWU_ + swz_pair(r0, 2*q)]);
            const vu2 b  = *(const vu2*)(&s1[r1 * ROWU_ + swz_pair(r1, 2*q)]);
            const vu2 cv = *(const vu2*)(&s1[r2 * ROWU_ + swz_pair(r2, 2*q)]);
            const vu2 d  = *(const vu2*)(&s1[r3 * ROWU_ + swz_pair(r3, 2*q)]);
            vf4 o;
            o.x = fmaxf(fmaxf(LO_(a.x), LO_(b.x)), fmaxf(LO_(cv.x), LO_(d.x)));
            o.y = fmaxf(fmaxf(HI_(a.x), HI_(b.x)), fmaxf(HI_(cv.x), HI_(d.x)));
            o.z = fmaxf(fmaxf(LO_(a.y), LO_(b.y)), fmaxf(LO_(cv.y), LO_(d.y)));
            o.w = fmaxf(fmaxf(HI_(a.y), HI_(b.y)), fmaxf(HI_(cv.y), HI_(d.y)));
            *(vf4*)(opb + (size_t)it * 128 * (H_ * W_)) = o;   // 16 full lines/instr
        }
    } else {
        const int q  = tid & 1;
        const int j0 = tid >> 1;                // j walks j0 + 256*it
        const int* ivp = idx + 4 * j0;
        float* opb = out + (size_t)(n * C1_ + j0) * (H_ * W_) + h * W_ + w0 + 4 * q;
        #pragma unroll 4
        for (int it = 0; it < 8; ++it) {
            const int4 iv = *(const int4*)(ivp + it * 1024);
            const int r0 = iv.x & (C1_-1), r1 = iv.y & (C1_-1);
            const int r2 = iv.z & (C1_-1), r3 = iv.w & (C1_-1);
            const vu2 a  = *(const vu2*)(&s1[r0 * ROWU_ + swz_pair(r0, 2*q)]);
            const vu2 b  = *(const vu2*)(&s1[r1 * ROWU_ + swz_pair(r1, 2*q)]);
            const vu2 cv = *(const vu2*)(&s1[r2 * ROWU_ + swz_pair(r2, 2*q)]);
            const vu2 d  = *(const vu2*)(&s1[r3 * ROWU_ + swz_pair(r3, 2*q)]);
            vf4 o;
            o.x = fmaxf(fmaxf(LO_(a.x), LO_(b.x)), fmaxf(LO_(cv.x), LO_(d.x)));
            o.y = fmaxf(fmaxf(HI_(a.x), HI_(b.x)), fmaxf(HI_(cv.x), HI_(d.x)));
            o.z = fmaxf(fmaxf(LO_(a.y), LO_(b.y)), fmaxf(LO_(cv.y), LO_(d.y)));
            o.w = fmaxf(fmaxf(HI_(a.y), HI_(b.y)), fmaxf(HI_(cv.y), HI_(d.y)));
            *(vf4*)(opb + (size_t)it * 256 * (H_ * W_)) = o;
        }
    }
}

__global__ __launch_bounds__(THREADS_, 4)
void rptn_fused(const float* __restrict__ x, const float* __restrict__ W1,
                const float* __restrict__ b1, const int* __restrict__ idx,
                float* __restrict__ out)
{
    __shared__ uint32_t s1[C1_ * ROWU_];       // 64 KB -> 2 blocks/CU
    const int tid  = threadIdx.x;
    const int b    = blockIdx.x;               // (n*56 + h)*4 + wsel
    const int wsel = b & 3;
    const int bh   = b >> 2;
    const int n    = bh / H_;
    const int h    = bh % H_;

    if (wsel == 0)      body<0>(s1, tid, n, h, 0,         x, W1, b1, idx, out);
    else if (wsel == 3) body<2>(s1, tid, n, h, 48,        x, W1, b1, idx, out);
    else                body<1>(s1, tid, n, h, wsel << 4, x, W1, b1, idx, out);
}

extern "C" void kernel_launch(void* const* d_in, const int* in_sizes, int n_in,
                              void* d_out, int out_size, void* d_ws, size_t ws_size,
                              hipStream_t stream)
{
    const float* x   = (const float*)d_in[0];
    const float* W1  = (const float*)d_in[1];
    const float* b1  = (const float*)d_in[2];
    const int* idxp  = (const int*)d_in[3];
    float* out       = (float*)d_out;

    dim3 grid(N_ * H_ * 4);   // 1792 blocks, exact coverage (16+16+16+8)
    dim3 block(THREADS_);
    hipLaunchKernelGGL(rptn_fused, grid, block, 0, stream, x, W1, b1, idxp, out);
}

// Round 9
// 61.882 us; speedup vs baseline: 3.1535x; 1.3040x over previous
//
#include <hip/hip_runtime.h>
#include <stdint.h>

#define N_       8
#define IC_      16
#define C1_      2048
#define H_       56
#define W_       56
#define THREADS_ 1024
#define ROWU_    8          // dwords per LDS row (16px bf16)
#define TPB_     7          // tiles per block (1792 tiles / 256 blocks)

typedef float    vf4 __attribute__((ext_vector_type(4)));
typedef uint32_t vu2 __attribute__((ext_vector_type(2)));

__device__ __forceinline__ uint32_t cvt_pk_bf16(float lo, float hi) {
    uint32_t r;
    asm("v_cvt_pk_bf16_f32 %0, %1, %2" : "=v"(r) : "v"(lo), "v"(hi));
    return r;   // [15:0]=bf16(lo) [31:16]=bf16(hi), RNE
}

#define LO_(u) __uint_as_float((u) << 16)
#define HI_(u) __uint_as_float((u) & 0xffff0000u)

// XOR pair-swizzle (r8): rows r, r+4, r+8, r+12 rotate their b64 pairs ->
// phase-1 write conflicts 16->4-way, gather reads <=4-way.
__device__ __forceinline__ int swz_pair(int row, int pair) {
    return (pair ^ (((row >> 2) & 3) << 1));
}

// Conv of one tile (all 2048 channels) into buf. TW=16 (w0=0/16/32) or 8 (w0=48).
template <int TW>
__device__ __forceinline__ void conv_tile(uint32_t* __restrict__ buf,
                                          const int n, const int h, const int w0,
                                          const int tid,
                                          const float* __restrict__ x,
                                          const float (&w)[2][9], const float (&bias)[2])
{
    #pragma unroll
    for (int p = 0; p < 2; ++p) {
        const int c  = p * THREADS_ + tid;
        const int ci = __builtin_amdgcn_readfirstlane(c >> 7);   // wave-uniform
        const float* xb = x + (size_t)((n * IC_ + ci) * H_) * W_;

        float win[3][TW + 2];                  // wave-uniform -> SGPR-resident
        #pragma unroll
        for (int rr = 0; rr < 3; ++rr) {
            const int r = h - 1 + rr;
            if ((unsigned)r < (unsigned)H_) {  // uniform branch
                const float* rp = xb + r * W_;
                win[rr][0] = (w0 == 0) ? 0.0f : rp[w0 - 1];
                #pragma unroll
                for (int v = 0; v < TW / 4; ++v) {
                    const vf4 t = *(const vf4*)(rp + w0 + 4 * v);   // 16B aligned
                    win[rr][1+4*v]=t.x; win[rr][2+4*v]=t.y;
                    win[rr][3+4*v]=t.z; win[rr][4+4*v]=t.w;
                }
                win[rr][TW + 1] = (TW == 8) ? 0.0f : rp[w0 + TW];   // right pad on tail
            } else {
                #pragma unroll
                for (int k = 0; k < TW + 2; ++k) win[rr][k] = 0.0f;
            }
        }

        float acc[TW];
        #pragma unroll
        for (int q = 0; q < TW; ++q) acc[q] = bias[p];
        #pragma unroll
        for (int dr = 0; dr < 3; ++dr)
            #pragma unroll
            for (int dc = 0; dc < 3; ++dc) {
                const float wk = w[p][dr * 3 + dc];
                #pragma unroll
                for (int q = 0; q < TW; ++q)
                    acc[q] = fmaf(win[dr][q + dc], wk, acc[q]);
            }

        uint32_t* row = &buf[c * ROWU_];
        #pragma unroll
        for (int m = 0; m < TW / 4; ++m) {
            vu2 pr;
            pr.x = cvt_pk_bf16(acc[4*m + 0], acc[4*m + 1]);
            pr.y = cvt_pk_bf16(acc[4*m + 2], acc[4*m + 3]);
            *(vu2*)(row + swz_pair(c, 2 * m)) = pr;   // ds_write_b64
        }
    }
}

// Pixel-major gather + max-over-4 + full-line float4 stores.
template <int TW>
__device__ __forceinline__ void gather_tile(const uint32_t* __restrict__ buf,
                                            const int n, const int h, const int w0,
                                            const int tid,
                                            const int* __restrict__ idx,
                                            float* __restrict__ out)
{
    constexpr int NV  = TW / 4;                 // float4 quads per channel (4 or 2)
    constexpr int ITS = (C1_ * NV) / THREADS_;  // 8 or 4
    constexpr int SH  = (NV == 4) ? 2 : 1;
    const int q  = tid & (NV - 1);
    const int jb = tid >> SH;
    #pragma unroll 4
    for (int it = 0; it < ITS; ++it) {
        const int j = it * (THREADS_ >> SH) + jb;
        const int4 iv = *(const int4*)(idx + 4 * j);
        const int r0 = iv.x & (C1_-1), r1 = iv.y & (C1_-1);
        const int r2 = iv.z & (C1_-1), r3 = iv.w & (C1_-1);
        const vu2 a  = *(const vu2*)(&buf[r0 * ROWU_ + swz_pair(r0, 2*q)]);
        const vu2 b  = *(const vu2*)(&buf[r1 * ROWU_ + swz_pair(r1, 2*q)]);
        const vu2 cv = *(const vu2*)(&buf[r2 * ROWU_ + swz_pair(r2, 2*q)]);
        const vu2 d  = *(const vu2*)(&buf[r3 * ROWU_ + swz_pair(r3, 2*q)]);
        vf4 o;
        o.x = fmaxf(fmaxf(LO_(a.x), LO_(b.x)), fmaxf(LO_(cv.x), LO_(d.x)));
        o.y = fmaxf(fmaxf(HI_(a.x), HI_(b.x)), fmaxf(HI_(cv.x), HI_(d.x)));
        o.z = fmaxf(fmaxf(LO_(a.y), LO_(b.y)), fmaxf(LO_(cv.y), LO_(d.y)));
        o.w = fmaxf(fmaxf(HI_(a.y), HI_(b.y)), fmaxf(HI_(cv.y), HI_(d.y)));
        float* op = out + (size_t)(n * C1_ + j) * (H_ * W_) + h * W_ + w0 + 4 * q;
        *(vf4*)op = o;                          // 4 lanes = one full 64B line
    }
}

// Persistent pipelined kernel: block owns TPB_ consecutive tiles; steady-state
// stage = { gather+store(t-1)  ||  conv(t) } between barriers -> stores issue
// continuously instead of in 50%-duty bursts.
__global__ __launch_bounds__(THREADS_, 4)
void rptn_pipe(const float* __restrict__ x, const float* __restrict__ W1,
               const float* __restrict__ b1, const int* __restrict__ idx,
               float* __restrict__ out)
{
    __shared__ uint32_t s[2][C1_ * ROWU_];     // 2 x 64 KB = 128 KB -> 1 block/CU
    const int tid = threadIdx.x;
    const int t0  = blockIdx.x * TPB_;

    // weights + bias hoisted once per block (amortized over 7 tiles)
    float w[2][9], bias[2];
    #pragma unroll
    for (int p = 0; p < 2; ++p) {
        const float* wp = W1 + (size_t)(p * THREADS_ + tid) * 9;
        #pragma unroll
        for (int k = 0; k < 9; ++k) w[p][k] = wp[k];
        bias[p] = b1[p * THREADS_ + tid];
    }

    int pn, ph, pw0, psel;                      // previous tile (pending gather)
    {
        psel = t0 & 3; const int bh = t0 >> 2;
        pn = bh / H_; ph = bh % H_; pw0 = psel * 16;   // 3*16 = 48 = tail tile
        if (psel == 3) conv_tile<8> (s[0], pn, ph, 48,  tid, x, w, bias);
        else           conv_tile<16>(s[0], pn, ph, pw0, tid, x, w, bias);
    }
    __syncthreads();

    #pragma unroll 1
    for (int k = 1; k < TPB_; ++k) {
        const int t   = t0 + k;
        const int sel = t & 3; const int bh = t >> 2;
        const int nn = bh / H_, hh = bh % H_, ww = sel * 16;

        // stores for tile t-1 issue early in the stage...
        if (psel == 3) gather_tile<8> (s[(k-1)&1], pn, ph, pw0, tid, idx, out);
        else           gather_tile<16>(s[(k-1)&1], pn, ph, pw0, tid, idx, out);
        // ...and overlap with conv of tile t into the other buffer
        if (sel == 3)  conv_tile<8> (s[k&1], nn, hh, 48, tid, x, w, bias);
        else           conv_tile<16>(s[k&1], nn, hh, ww, tid, x, w, bias);

        __syncthreads();
        pn = nn; ph = hh; pw0 = ww; psel = sel;
    }
    if (psel == 3) gather_tile<8> (s[(TPB_-1)&1], pn, ph, pw0, tid, idx, out);
    else           gather_tile<16>(s[(TPB_-1)&1], pn, ph, pw0, tid, idx, out);
}

extern "C" void kernel_launch(void* const* d_in, const int* in_sizes, int n_in,
                              void* d_out, int out_size, void* d_ws, size_t ws_size,
                              hipStream_t stream)
{
    const float* x   = (const float*)d_in[0];
    const float* W1  = (const float*)d_in[1];
    const float* b1  = (const float*)d_in[2];
    const int* idxp  = (const int*)d_in[3];
    float* out       = (float*)d_out;

    dim3 grid(256);              // 1 block per CU; 7 tiles each = 1792 tiles exact
    dim3 block(THREADS_);
    hipLaunchKernelGGL(rptn_pipe, grid, block, 0, stream, x, W1, b1, idxp, out);
}